// Round 2
// baseline (567.740 us; speedup 1.0000x reference)
//
#include <hip/hip_runtime.h>
#include <stdint.h>

// ---------------- common types / helpers ----------------

typedef short bf16x8 __attribute__((ext_vector_type(8)));
typedef float f32x4 __attribute__((ext_vector_type(4)));

struct alignas(8) us4 { unsigned short x, y, z, w; };

__device__ __forceinline__ unsigned short f32_to_bf16(float f) {
  union { float f; uint32_t u; } v; v.f = f;
  uint32_t u = v.u;
  uint32_t r = (u + 0x7fffu + ((u >> 16) & 1u)) >> 16;  // RNE
  return (unsigned short)r;
}

__device__ __forceinline__ float bf16_to_f32(unsigned short h) {
  union { uint32_t u; float f; } v; v.u = ((uint32_t)h) << 16;
  return v.f;
}

// pack two f32 into bf16x2 by truncation: one v_perm_b32
__device__ __forceinline__ uint32_t pack_bf16_trunc(float lo, float hi) {
  union { float f; uint32_t u; } a, b; a.f = lo; b.f = hi;
  return __builtin_amdgcn_perm(b.u, a.u, 0x07060302u);  // [lo.hi16, hi.hi16]
}

// async global->LDS, 16B per lane; LDS dest is wave-uniform base + lane*16
__device__ __forceinline__ void g2l16(const unsigned short* g, unsigned short* l) {
  __builtin_amdgcn_global_load_lds((__attribute__((address_space(1))) void*)g,
                                   (__attribute__((address_space(3))) void*)l,
                                   16, 0, 0);
}

// ---------------- problem constants ----------------
// B=128, S=512, D=768, NH=8, HD=96, HID=384

#define N_X   50331648   // 128*512*768
#define N_P   589824     // 8*96*768
#define N_W1  294912     // 8*384*96
#define N_W2  294912     // 8*96*384
#define N_HI  50331648   // 8*128*512*96

// ---------------- kernel 0: fp32 -> bf16 cast ----------------

__global__ __launch_bounds__(256) void cast_f32_bf16(
    const float* __restrict__ src, unsigned short* __restrict__ dst, int n4) {
  int idx = blockIdx.x * 256 + threadIdx.x;
  if (idx >= n4) return;
  float4 v = ((const float4*)src)[idx];
  us4 o;
  o.x = f32_to_bf16(v.x);
  o.y = f32_to_bf16(v.y);
  o.z = f32_to_bf16(v.z);
  o.w = f32_to_bf16(v.w);
  ((us4*)dst)[idx] = o;
}

// ---------------- kernel 1: Hi = X @ P^T + bP ----------------
// v3: granule XOR-swizzle on As/Bs ([row][32] tiles). Swizzle is applied on
// the GLOBAL source address (g2l16 dest must stay linear, m173 pattern);
// reads use pos = q ^ ((r>>1)&3) -> 8 distinct bank-quad starts per 8 lanes.

__global__ __launch_bounds__(256) void gemm_hi(
    const unsigned short* __restrict__ Xbf,
    const unsigned short* __restrict__ Pbf,
    const float* __restrict__ bP,
    unsigned short* __restrict__ Hi) {
  __shared__ __align__(16) unsigned short As[128 * 32];
  __shared__ __align__(16) unsigned short Bs[128 * 32];

  const int tid = threadIdx.x;
  const int w = tid >> 6;
  const int lane = tid & 63;
  const int r = lane & 15;
  const int q = lane >> 4;
  const int bn = blockIdx.x;  // 0..5
  const int bm = blockIdx.y;  // 0..511
  const int wr = w >> 1, wc = w & 1;
  const int psw = q ^ ((r >> 1) & 3);  // swizzled read granule

  f32x4 acc[4][4];
#pragma unroll
  for (int a = 0; a < 4; ++a)
#pragma unroll
    for (int c = 0; c < 4; ++c) acc[a][c] = (f32x4){0.f, 0.f, 0.f, 0.f};

  const int ldr = lane >> 2;
  // source granule = (lane&3) ^ ((row_d>>1)&3); row_d = w*16 + ldr -> (ldr>>1)&3
  const int ldc = ((lane & 3) ^ ((lane >> 3) & 3)) * 8;
  const unsigned short* Abase = Xbf + (size_t)(bm * 128) * 768 + ldc;
  const unsigned short* Bbase = Pbf + (size_t)(bn * 128) * 768 + ldc;

  for (int k0 = 0; k0 < 768; k0 += 32) {
    __syncthreads();
    g2l16(Abase + (size_t)(w * 16 + ldr) * 768 + k0, &As[w * 512]);
    g2l16(Abase + (size_t)(64 + w * 16 + ldr) * 768 + k0, &As[(4 + w) * 512]);
    g2l16(Bbase + (size_t)(w * 16 + ldr) * 768 + k0, &Bs[w * 512]);
    g2l16(Bbase + (size_t)(64 + w * 16 + ldr) * 768 + k0, &Bs[(4 + w) * 512]);
    __syncthreads();

    bf16x8 af[4], bfr[4];
#pragma unroll
    for (int t = 0; t < 4; ++t)
      af[t] = *(const bf16x8*)&As[(wr * 64 + t * 16 + r) * 32 + psw * 8];
#pragma unroll
    for (int t = 0; t < 4; ++t)
      bfr[t] = *(const bf16x8*)&Bs[(wc * 64 + t * 16 + r) * 32 + psw * 8];
#pragma unroll
    for (int mt = 0; mt < 4; ++mt)
#pragma unroll
      for (int nt = 0; nt < 4; ++nt)
        acc[mt][nt] = __builtin_amdgcn_mfma_f32_16x16x32_bf16(
            af[mt], bfr[nt], acc[mt][nt], 0, 0, 0);
  }

  const int bb = bm >> 2;
  const int sb = (bm & 3) * 128 + wr * 64;
#pragma unroll
  for (int nt = 0; nt < 4; ++nt) {
    const int n0 = bn * 128 + wc * 64 + nt * 16;
    const int hd = n0 / 96;
    const int h = n0 - hd * 96 + r;
    const float bias = bP[n0 + r];
    unsigned short* obase = Hi + (size_t)(hd * 128 + bb) * 512 * 96 + h;
#pragma unroll
    for (int mt = 0; mt < 4; ++mt) {
#pragma unroll
      for (int rg = 0; rg < 4; ++rg) {
        const int s = sb + mt * 16 + q * 4 + rg;
        obase[(size_t)s * 96] = f32_to_bf16(acc[mt][nt][rg] + bias);
      }
    }
  }
}

// ---------------- kernel 2: fused per-head MLP -> logits -> softmax -> pool ----------------
// v3 changes vs v2:
//  * LDS granule XOR-swizzle (pos = p ^ ((row>>1)&3)) on Ys, W1q, W2q via
//    pre-swizzled global source addresses; reads use q ^ ((r>>1)&3).
//  * Y B-fragments cached in registers per chunk (loaded at ph0, reused 4 phases).
//  * Fs shares W1q's LDS region (U); barrier between GEMM2 reads and epilogue writes.
//  * W2q staged AFTER the weights-ready barrier so its flight overlaps GEMM2.
// LDS ~76.7 KB -> 2 blocks/CU.

__global__ __launch_bounds__(256, 2) void mlp_pool(
    const unsigned short* __restrict__ Hi,
    const unsigned short* __restrict__ W1bf,  // (8*384) x 96
    const unsigned short* __restrict__ W2bf,  // (8*96) x 384
    const float* __restrict__ b1,             // 8*384
    const float* __restrict__ b2,             // 8*96
    const float* __restrict__ mask,           // B x S
    float* __restrict__ out) {                // B x 768
  __shared__ __align__(16) unsigned short Ys[128 * 96];   // [s][96] swizzled
  __shared__ __align__(16) unsigned short U[128 * 104];   // W1q [f][96] swz -> Fs [s][104]
  __shared__ __align__(16) unsigned short Ws2[3 * 96 * 32];  // W2q [kb][h][32] swz
  __shared__ __align__(16) float b1s[384];
  __shared__ __align__(16) float b2s[96];
  __shared__ float bias_s[512];
  __shared__ float redA[4][96];
  __shared__ float redB[4][96];

  const int x = blockIdx.x;
  const int b = x & 127;    // batch
  const int hd = x >> 7;    // head (slowest -> weight L2 sharing)

  const int tid = threadIdx.x;
  const int w = tid >> 6;
  const int lane = tid & 63;
  const int r = lane & 15;
  const int q = lane >> 4;
  const int psw = q ^ ((r >> 1) & 3);  // swizzled read granule (row ≡ r mod 16)

  if (tid < 96) b2s[tid] = b2[hd * 96 + tid];
  for (int i = tid; i < 384; i += 256) b1s[i] = b1[hd * 384 + i];
  for (int s = tid; s < 512; s += 256)
    bias_s[s] = mask[b * 512 + s] > 0.5f ? 0.f : -1e30f;

  float m_run[6], l_run[6], v_run[6];
#pragma unroll
  for (int nt = 0; nt < 6; ++nt) { m_run[nt] = -3e30f; l_run[nt] = 0.f; v_run[nt] = 0.f; }

  for (int c = 0; c < 4; ++c) {
    __syncthreads();  // prev pooling done reading Ys/redA; prev GEMM3 done with U/Ws2

    // stage Y chunk into swizzled [s][96]: dest linear, source granule pre-swizzled
    const unsigned short* ysrc =
        Hi + ((size_t)(hd * 128 + b) * 512 + c * 128) * 96;
#pragma unroll
    for (int it = 0; it < 6; ++it) {
      const int ch = (it * 4 + w) * 64 + lane;  // 0..1535
      const int row = ch / 12;
      const int g = ch - row * 12;
      const int kb = g >> 2, p = g & 3;
      g2l16(ysrc + (size_t)row * 96 + kb * 32 + (p ^ ((row >> 1) & 3)) * 8,
            &Ys[(it * 4 + w) * 512]);
    }

    f32x4 acc3[2][6];
#pragma unroll
    for (int sp = 0; sp < 2; ++sp)
#pragma unroll
      for (int nt = 0; nt < 6; ++nt) acc3[sp][nt] = (f32x4){0.f, 0.f, 0.f, 0.f};

    bf16x8 yfrg[2][3];

    for (int ph = 0; ph < 4; ++ph) {
      if (ph) __syncthreads();  // GEMM3(ph-1) done reading U(Fs)/Ws2

      // stage W1 quarter into U, [f][96] swizzled
      const unsigned short* w1src = W1bf + ((size_t)hd * 384 + ph * 96) * 96;
#pragma unroll
      for (int it = 0; it < 4; ++it) {
        const int ch = (it * 4 + w) * 64 + lane;  // 0..1023
        const int row = ch / 12;
        const int g = ch - row * 12;
        const int kb = g >> 2, p = g & 3;
        g2l16(w1src + (size_t)row * 96 + kb * 32 + (p ^ ((row >> 1) & 3)) * 8,
              &U[(it * 4 + w) * 512]);
      }
      if (w < 2) {
        const int ch = 1024 + w * 64 + lane;  // 1024..1151
        const int row = ch / 12;
        const int g = ch - row * 12;
        const int kb = g >> 2, p = g & 3;
        g2l16(w1src + (size_t)row * 96 + kb * 32 + (p ^ ((row >> 1) & 3)) * 8,
              &U[(16 + w) * 512]);
      }
      __syncthreads();  // W1q ready (and Ys on ph==0)

      // stage W2 quarter NOW -> flight overlaps GEMM2; drains at next barrier.
      // layout [kb][h][32] swizzled; Ws2 free since prev GEMM3 (barrier above).
      const unsigned short* w2src = W2bf + (size_t)hd * 96 * 384 + ph * 96;
#pragma unroll
      for (int it = 0; it < 4; ++it) {
        const int ch = (it * 4 + w) * 64 + lane;  // 0..1023
        const int kb = ch / 384;
        const int rem = ch - kb * 384;
        const int hh = rem >> 2, p = rem & 3;
        g2l16(w2src + (size_t)hh * 384 + kb * 32 + (p ^ ((hh >> 1) & 3)) * 8,
              &Ws2[(it * 4 + w) * 512]);
      }
      if (w < 2) {
        const int ch = 1024 + w * 64 + lane;  // 1024..1151
        const int kb = ch / 384;
        const int rem = ch - kb * 384;
        const int hh = rem >> 2, p = rem & 3;
        g2l16(w2src + (size_t)hh * 384 + kb * 32 + (p ^ ((hh >> 1) & 3)) * 8,
              &Ws2[(16 + w) * 512]);
      }

      if (ph == 0) {
#pragma unroll
        for (int sp = 0; sp < 2; ++sp)
#pragma unroll
          for (int kb = 0; kb < 3; ++kb)
            yfrg[sp][kb] =
                *(const bf16x8*)&Ys[((w * 2 + sp) * 16 + r) * 96 + kb * 32 + psw * 8];
      }

      // GEMM2: F^T = W1q @ Y^T. M=96(f), N=128(s), K=96. Y frags from regs.
      f32x4 acc2[6][2];
#pragma unroll
      for (int ft = 0; ft < 6; ++ft)
#pragma unroll
        for (int sp = 0; sp < 2; ++sp) acc2[ft][sp] = (f32x4){0.f, 0.f, 0.f, 0.f};
#pragma unroll
      for (int kb = 0; kb < 3; ++kb) {
#pragma unroll
        for (int ft = 0; ft < 6; ++ft) {
          bf16x8 afrg = *(const bf16x8*)&U[(ft * 16 + r) * 96 + kb * 32 + psw * 8];
#pragma unroll
          for (int sp = 0; sp < 2; ++sp)
            acc2[ft][sp] = __builtin_amdgcn_mfma_f32_16x16x32_bf16(
                afrg, yfrg[sp][kb], acc2[ft][sp], 0, 0, 0);
        }
      }
      __syncthreads();  // all waves done reading W1q from U (also drains W2q loads)

      // epilogue: +b1, relu, pack pairs, b64 write Fs into U ([s][104])
#pragma unroll
      for (int ft = 0; ft < 6; ++ft) {
        float4 bv = *(const float4*)&b1s[ph * 96 + ft * 16 + q * 4];
#pragma unroll
        for (int sp = 0; sp < 2; ++sp) {
          const int s = (w * 2 + sp) * 16 + r;
          float v0 = fmaxf(acc2[ft][sp][0] + bv.x, 0.f);
          float v1 = fmaxf(acc2[ft][sp][1] + bv.y, 0.f);
          float v2 = fmaxf(acc2[ft][sp][2] + bv.z, 0.f);
          float v3 = fmaxf(acc2[ft][sp][3] + bv.w, 0.f);
          uint2 pk;
          pk.x = pack_bf16_trunc(v0, v1);
          pk.y = pack_bf16_trunc(v2, v3);
          *(uint2*)((uint32_t*)&U[0] + s * 52 + ft * 8 + q * 2) = pk;
        }
      }
      __syncthreads();  // Fs ready

      // GEMM3 partial: M=128(s), N=96(h), K=96 this phase.
#pragma unroll
      for (int kb = 0; kb < 3; ++kb) {
        bf16x8 afrg[2];
#pragma unroll
        for (int sp = 0; sp < 2; ++sp)
          afrg[sp] = *(const bf16x8*)&U[((w * 2 + sp) * 16 + r) * 104 + kb * 32 + q * 8];
#pragma unroll
        for (int nt = 0; nt < 6; ++nt) {
          bf16x8 bfrg = *(const bf16x8*)&Ws2[(kb * 96 + nt * 16 + r) * 32 + psw * 8];
#pragma unroll
          for (int sp = 0; sp < 2; ++sp)
            acc3[sp][nt] = __builtin_amdgcn_mfma_f32_16x16x32_bf16(
                afrg[sp], bfrg, acc3[sp][nt], 0, 0, 0);
        }
      }
    }

    // ---- chunk pooling: online softmax accumulate ----
    // C-layout: h = nt*16 + r, s_local = (w*2+sp)*16 + q*4 + rg
#pragma unroll
    for (int nt = 0; nt < 6; ++nt) {
      const int h = nt * 16 + r;
      const float b2v = b2s[h];
      float lm = -3e30f;
#pragma unroll
      for (int sp = 0; sp < 2; ++sp) {
#pragma unroll
        for (int rg = 0; rg < 4; ++rg) {
          const int sl = (w * 2 + sp) * 16 + q * 4 + rg;
          float lg = acc3[sp][nt][rg] + b2v + bias_s[c * 128 + sl];
          lm = fmaxf(lm, lg);
        }
      }
      lm = fmaxf(lm, __shfl_xor(lm, 16));
      lm = fmaxf(lm, __shfl_xor(lm, 32));
      if (q == 0) redA[w][h] = lm;
    }
    __syncthreads();  // chunk-max ready across waves
#pragma unroll
    for (int nt = 0; nt < 6; ++nt) {
      const int h = nt * 16 + r;
      // swizzled Ys scalar read setup: element h granule
      const int gh = nt * 2 + (r >> 3);
      const int kbh = gh >> 2, ph_ = gh & 3;
      const int hlo = r & 7;
      const float cm = fmaxf(fmaxf(redA[0][h], redA[1][h]),
                             fmaxf(redA[2][h], redA[3][h]));
      const float mnew = fmaxf(m_run[nt], cm);
      const float sc = __expf(m_run[nt] - mnew);
      m_run[nt] = mnew;
      float lacc = l_run[nt] * sc;
      float vacc = v_run[nt] * sc;
      const float b2v = b2s[h];
#pragma unroll
      for (int sp = 0; sp < 2; ++sp) {
#pragma unroll
        for (int rg = 0; rg < 4; ++rg) {
          const int sl = (w * 2 + sp) * 16 + q * 4 + rg;
          float lg = acc3[sp][nt][rg] + b2v + bias_s[c * 128 + sl];
          float e = __expf(lg - mnew);
          lacc += e;
          const int pos = ph_ ^ ((sl >> 1) & 3);
          vacc += e * bf16_to_f32(Ys[sl * 96 + kbh * 32 + pos * 8 + hlo]);
        }
      }
      l_run[nt] = lacc;
      v_run[nt] = vacc;
    }
  }

  // ---- final reduce: sum l,v across q-groups then waves; out = v/l ----
  __syncthreads();  // redA/redB free
#pragma unroll
  for (int nt = 0; nt < 6; ++nt) {
    float ls = l_run[nt], vs = v_run[nt];
    ls += __shfl_xor(ls, 16);
    vs += __shfl_xor(vs, 16);
    ls += __shfl_xor(ls, 32);
    vs += __shfl_xor(vs, 32);
    if (q == 0) {
      redA[w][nt * 16 + r] = ls;
      redB[w][nt * 16 + r] = vs;
    }
  }
  __syncthreads();
  if (tid < 96) {
    float ls = redA[0][tid] + redA[1][tid] + redA[2][tid] + redA[3][tid];
    float vs = redB[0][tid] + redB[1][tid] + redB[2][tid] + redB[3][tid];
    out[(size_t)b * 768 + hd * 96 + tid] = vs / ls;
  }
}

// ---------------- launcher ----------------

extern "C" void kernel_launch(void* const* d_in, const int* in_sizes, int n_in,
                              void* d_out, int out_size, void* d_ws, size_t ws_size,
                              hipStream_t stream) {
  const float* X    = (const float*)d_in[0];
  const float* mask = (const float*)d_in[1];
  const float* P    = (const float*)d_in[2];
  const float* bP   = (const float*)d_in[3];
  const float* W1   = (const float*)d_in[4];
  const float* b1   = (const float*)d_in[5];
  const float* W2   = (const float*)d_in[6];
  const float* b2   = (const float*)d_in[7];
  float* out = (float*)d_out;
  (void)in_sizes; (void)n_in; (void)out_size; (void)ws_size;

  unsigned short* Xbf  = (unsigned short*)d_ws;
  unsigned short* Pbf  = Xbf + N_X;
  unsigned short* W1bf = Pbf + N_P;
  unsigned short* W2bf = W1bf + N_W1;
  unsigned short* Hi   = W2bf + N_W2;

  cast_f32_bf16<<<N_X / 4 / 256, 256, 0, stream>>>(X, Xbf, N_X / 4);
  cast_f32_bf16<<<N_P / 4 / 256, 256, 0, stream>>>(P, Pbf, N_P / 4);
  cast_f32_bf16<<<N_W1 / 4 / 256, 256, 0, stream>>>(W1, W1bf, N_W1 / 4);
  cast_f32_bf16<<<N_W2 / 4 / 256, 256, 0, stream>>>(W2, W2bf, N_W2 / 4);

  gemm_hi<<<dim3(6, 512), 256, 0, stream>>>(Xbf, Pbf, bP, Hi);
  mlp_pool<<<8 * 128, 256, 0, stream>>>(Hi, W1bf, W2bf, b1, b2, mask, out);
}

// Round 3
// 548.905 us; speedup vs baseline: 1.0343x; 1.0343x over previous
//
#include <hip/hip_runtime.h>
#include <stdint.h>

// ---------------- common types / helpers ----------------

typedef short bf16x8 __attribute__((ext_vector_type(8)));
typedef float f32x4 __attribute__((ext_vector_type(4)));

struct alignas(8) us4 { unsigned short x, y, z, w; };

__device__ __forceinline__ unsigned short f32_to_bf16(float f) {
  union { float f; uint32_t u; } v; v.f = f;
  uint32_t u = v.u;
  uint32_t r = (u + 0x7fffu + ((u >> 16) & 1u)) >> 16;  // RNE
  return (unsigned short)r;
}

__device__ __forceinline__ float bf16_to_f32(unsigned short h) {
  union { uint32_t u; float f; } v; v.u = ((uint32_t)h) << 16;
  return v.f;
}

// pack two f32 into bf16x2 by truncation: one v_perm_b32
__device__ __forceinline__ uint32_t pack_bf16_trunc(float lo, float hi) {
  union { float f; uint32_t u; } a, b; a.f = lo; b.f = hi;
  return __builtin_amdgcn_perm(b.u, a.u, 0x07060302u);  // [lo.hi16, hi.hi16]
}

// async global->LDS, 16B per lane; LDS dest is wave-uniform base + lane*16
__device__ __forceinline__ void g2l16(const unsigned short* g, unsigned short* l) {
  __builtin_amdgcn_global_load_lds((__attribute__((address_space(1))) void*)g,
                                   (__attribute__((address_space(3))) void*)l,
                                   16, 0, 0);
}

// ---------------- problem constants ----------------
// B=128, S=512, D=768, NH=8, HD=96, HID=384

#define N_X   50331648   // 128*512*768
#define N_P   589824     // 8*96*768
#define N_W1  294912     // 8*384*96
#define N_W2  294912     // 8*96*384
#define N_HI  50331648   // 8*128*512*96

// ---------------- kernel 0: fp32 -> bf16 cast ----------------

__global__ __launch_bounds__(256) void cast_f32_bf16(
    const float* __restrict__ src, unsigned short* __restrict__ dst, int n4) {
  int idx = blockIdx.x * 256 + threadIdx.x;
  if (idx >= n4) return;
  float4 v = ((const float4*)src)[idx];
  us4 o;
  o.x = f32_to_bf16(v.x);
  o.y = f32_to_bf16(v.y);
  o.z = f32_to_bf16(v.z);
  o.w = f32_to_bf16(v.w);
  ((us4*)dst)[idx] = o;
}

// ---------------- kernel 1: Hi = X @ P^T + bP ----------------
// granule XOR-swizzle on As/Bs (source-side pre-swizzle, linear g2l16 dest).

__global__ __launch_bounds__(256) void gemm_hi(
    const unsigned short* __restrict__ Xbf,
    const unsigned short* __restrict__ Pbf,
    const float* __restrict__ bP,
    unsigned short* __restrict__ Hi) {
  __shared__ __align__(16) unsigned short As[128 * 32];
  __shared__ __align__(16) unsigned short Bs[128 * 32];

  const int tid = threadIdx.x;
  const int w = tid >> 6;
  const int lane = tid & 63;
  const int r = lane & 15;
  const int q = lane >> 4;
  const int bn = blockIdx.x;  // 0..5
  const int bm = blockIdx.y;  // 0..511
  const int wr = w >> 1, wc = w & 1;
  const int psw = q ^ ((r >> 1) & 3);  // swizzled read granule

  f32x4 acc[4][4];
#pragma unroll
  for (int a = 0; a < 4; ++a)
#pragma unroll
    for (int c = 0; c < 4; ++c) acc[a][c] = (f32x4){0.f, 0.f, 0.f, 0.f};

  const int ldr = lane >> 2;
  // source granule = (lane&3) ^ ((row_d>>1)&3); row_d = w*16 + ldr -> (ldr>>1)&3
  const int ldc = ((lane & 3) ^ ((lane >> 3) & 3)) * 8;
  const unsigned short* Abase = Xbf + (size_t)(bm * 128) * 768 + ldc;
  const unsigned short* Bbase = Pbf + (size_t)(bn * 128) * 768 + ldc;

  for (int k0 = 0; k0 < 768; k0 += 32) {
    __syncthreads();
    g2l16(Abase + (size_t)(w * 16 + ldr) * 768 + k0, &As[w * 512]);
    g2l16(Abase + (size_t)(64 + w * 16 + ldr) * 768 + k0, &As[(4 + w) * 512]);
    g2l16(Bbase + (size_t)(w * 16 + ldr) * 768 + k0, &Bs[w * 512]);
    g2l16(Bbase + (size_t)(64 + w * 16 + ldr) * 768 + k0, &Bs[(4 + w) * 512]);
    __syncthreads();

    bf16x8 af[4], bfr[4];
#pragma unroll
    for (int t = 0; t < 4; ++t)
      af[t] = *(const bf16x8*)&As[(wr * 64 + t * 16 + r) * 32 + psw * 8];
#pragma unroll
    for (int t = 0; t < 4; ++t)
      bfr[t] = *(const bf16x8*)&Bs[(wc * 64 + t * 16 + r) * 32 + psw * 8];
#pragma unroll
    for (int mt = 0; mt < 4; ++mt)
#pragma unroll
      for (int nt = 0; nt < 4; ++nt)
        acc[mt][nt] = __builtin_amdgcn_mfma_f32_16x16x32_bf16(
            af[mt], bfr[nt], acc[mt][nt], 0, 0, 0);
  }

  const int bb = bm >> 2;
  const int sb = (bm & 3) * 128 + wr * 64;
#pragma unroll
  for (int nt = 0; nt < 4; ++nt) {
    const int n0 = bn * 128 + wc * 64 + nt * 16;
    const int hd = n0 / 96;
    const int h = n0 - hd * 96 + r;
    const float bias = bP[n0 + r];
    unsigned short* obase = Hi + (size_t)(hd * 128 + bb) * 512 * 96 + h;
#pragma unroll
    for (int mt = 0; mt < 4; ++mt) {
#pragma unroll
      for (int rg = 0; rg < 4; ++rg) {
        const int s = sb + mt * 16 + q * 4 + rg;
        obase[(size_t)s * 96] = f32_to_bf16(acc[mt][nt][rg] + bias);
      }
    }
  }
}

// ---------------- kernel 2: fused per-head MLP -> logits -> softmax -> pool ----------------
// v4 = v2 (round-1) phase structure + v3 LDS swizzles ONLY.
//  * R1 structure: separate Ws/Fs buffers; Y frags read from LDS each phase;
//    W2 staged between Fs-ready and Ws-ready barriers. (v3's yfrg caching +
//    W2-early/U-sharing caused scratch spill: WRITE_SIZE 384K->48.5M.)
//  * v3 swizzles kept: pre-swizzled g2l16 sources for Ys/W1q/W2q, psw frag
//    reads, swizzled pooling scalar reads (conflicts 17.3M->4.7M proven).
// LDS ~76.7 KB -> 2 blocks/CU.

__global__ __launch_bounds__(256, 2) void mlp_pool(
    const unsigned short* __restrict__ Hi,
    const unsigned short* __restrict__ W1bf,  // (8*384) x 96
    const unsigned short* __restrict__ W2bf,  // (8*96) x 384
    const float* __restrict__ b1,             // 8*384
    const float* __restrict__ b2,             // 8*96
    const float* __restrict__ mask,           // B x S
    float* __restrict__ out) {                // B x 768
  __shared__ __align__(16) unsigned short Ys[128 * 96];   // [s][96] swizzled
  __shared__ __align__(16) unsigned short Ws[96 * 96];    // W1q [f][96] / W2q [kb][h][32], swizzled
  __shared__ __align__(16) unsigned short Fs[128 * 104];  // [s][96 + 8 pad]
  __shared__ __align__(16) float b1s[384];
  __shared__ __align__(16) float b2s[96];
  __shared__ float bias_s[512];
  __shared__ float redA[4][96];
  __shared__ float redB[4][96];

  const int x = blockIdx.x;
  const int b = x & 127;    // batch
  const int hd = x >> 7;    // head (slowest -> weight L2 sharing)

  const int tid = threadIdx.x;
  const int w = tid >> 6;
  const int lane = tid & 63;
  const int r = lane & 15;
  const int q = lane >> 4;
  const int psw = q ^ ((r >> 1) & 3);  // swizzled read granule

  if (tid < 96) b2s[tid] = b2[hd * 96 + tid];
  for (int i = tid; i < 384; i += 256) b1s[i] = b1[hd * 384 + i];
  for (int s = tid; s < 512; s += 256)
    bias_s[s] = mask[b * 512 + s] > 0.5f ? 0.f : -1e30f;

  float m_run[6], l_run[6], v_run[6];
#pragma unroll
  for (int nt = 0; nt < 6; ++nt) { m_run[nt] = -3e30f; l_run[nt] = 0.f; v_run[nt] = 0.f; }

  for (int c = 0; c < 4; ++c) {
    __syncthreads();  // prev pooling done reading Ys/redA; prev GEMM3 done with Ws/Fs

    // stage Y chunk into swizzled [s][96]: dest linear, source granule pre-swizzled
    const unsigned short* ysrc =
        Hi + ((size_t)(hd * 128 + b) * 512 + c * 128) * 96;
#pragma unroll
    for (int it = 0; it < 6; ++it) {
      const int ch = (it * 4 + w) * 64 + lane;  // 0..1535
      const int row = ch / 12;
      const int g = ch - row * 12;
      const int kb = g >> 2, p = g & 3;
      g2l16(ysrc + (size_t)row * 96 + kb * 32 + (p ^ ((row >> 1) & 3)) * 8,
            &Ys[(it * 4 + w) * 512]);
    }

    f32x4 acc3[2][6];
#pragma unroll
    for (int sp = 0; sp < 2; ++sp)
#pragma unroll
      for (int nt = 0; nt < 6; ++nt) acc3[sp][nt] = (f32x4){0.f, 0.f, 0.f, 0.f};

    for (int ph = 0; ph < 4; ++ph) {
      if (ph) __syncthreads();  // GEMM3(ph-1) done reading Ws/Fs

      // stage W1 quarter into Ws, [f][96] swizzled
      const unsigned short* w1src = W1bf + ((size_t)hd * 384 + ph * 96) * 96;
#pragma unroll
      for (int it = 0; it < 4; ++it) {
        const int ch = (it * 4 + w) * 64 + lane;  // 0..1023
        const int row = ch / 12;
        const int g = ch - row * 12;
        const int kb = g >> 2, p = g & 3;
        g2l16(w1src + (size_t)row * 96 + kb * 32 + (p ^ ((row >> 1) & 3)) * 8,
              &Ws[(it * 4 + w) * 512]);
      }
      if (w < 2) {
        const int ch = 1024 + w * 64 + lane;  // 1024..1151
        const int row = ch / 12;
        const int g = ch - row * 12;
        const int kb = g >> 2, p = g & 3;
        g2l16(w1src + (size_t)row * 96 + kb * 32 + (p ^ ((row >> 1) & 3)) * 8,
              &Ws[(16 + w) * 512]);
      }
      __syncthreads();  // W1q ready (and Ys on ph==0)

      // GEMM2: F^T = W1q @ Y^T. M=96(f), N=128(s), K=96. Frags from LDS (swizzled).
      f32x4 acc2[6][2];
#pragma unroll
      for (int ft = 0; ft < 6; ++ft)
#pragma unroll
        for (int sp = 0; sp < 2; ++sp) acc2[ft][sp] = (f32x4){0.f, 0.f, 0.f, 0.f};
#pragma unroll
      for (int kb = 0; kb < 3; ++kb) {
        bf16x8 bfrg[2];
#pragma unroll
        for (int sp = 0; sp < 2; ++sp)
          bfrg[sp] = *(const bf16x8*)&Ys[((w * 2 + sp) * 16 + r) * 96 + kb * 32 + psw * 8];
#pragma unroll
        for (int ft = 0; ft < 6; ++ft) {
          bf16x8 afrg = *(const bf16x8*)&Ws[(ft * 16 + r) * 96 + kb * 32 + psw * 8];
#pragma unroll
          for (int sp = 0; sp < 2; ++sp)
            acc2[ft][sp] = __builtin_amdgcn_mfma_f32_16x16x32_bf16(
                afrg, bfrg[sp], acc2[ft][sp], 0, 0, 0);
        }
      }
      // epilogue: +b1, relu, pack pairs, b64 write to Fs ([s][104], unswizzled)
#pragma unroll
      for (int ft = 0; ft < 6; ++ft) {
        float4 bv = *(const float4*)&b1s[ph * 96 + ft * 16 + q * 4];
#pragma unroll
        for (int sp = 0; sp < 2; ++sp) {
          const int s = (w * 2 + sp) * 16 + r;
          float v0 = fmaxf(acc2[ft][sp][0] + bv.x, 0.f);
          float v1 = fmaxf(acc2[ft][sp][1] + bv.y, 0.f);
          float v2 = fmaxf(acc2[ft][sp][2] + bv.z, 0.f);
          float v3 = fmaxf(acc2[ft][sp][3] + bv.w, 0.f);
          uint2 pk;
          pk.x = pack_bf16_trunc(v0, v1);
          pk.y = pack_bf16_trunc(v2, v3);
          *(uint2*)((uint32_t*)&Fs[0] + s * 52 + ft * 8 + q * 2) = pk;
        }
      }
      __syncthreads();  // Fs ready; Ws (W1q) consumed

      // stage W2 quarter into Ws, [kb][h][32] swizzled
      const unsigned short* w2src = W2bf + (size_t)hd * 96 * 384 + ph * 96;
#pragma unroll
      for (int it = 0; it < 4; ++it) {
        const int ch = (it * 4 + w) * 64 + lane;  // 0..1023
        const int kb = ch / 384;
        const int rem = ch - kb * 384;
        const int hh = rem >> 2, p = rem & 3;
        g2l16(w2src + (size_t)hh * 384 + kb * 32 + (p ^ ((hh >> 1) & 3)) * 8,
              &Ws[(it * 4 + w) * 512]);
      }
      if (w < 2) {
        const int ch = 1024 + w * 64 + lane;  // 1024..1151
        const int kb = ch / 384;
        const int rem = ch - kb * 384;
        const int hh = rem >> 2, p = rem & 3;
        g2l16(w2src + (size_t)hh * 384 + kb * 32 + (p ^ ((hh >> 1) & 3)) * 8,
              &Ws[(16 + w) * 512]);
      }
      __syncthreads();  // Ws(W2q) ready

      // GEMM3 partial: M=128(s), N=96(h), K=96 this phase.
#pragma unroll
      for (int kb = 0; kb < 3; ++kb) {
        bf16x8 afrg[2];
#pragma unroll
        for (int sp = 0; sp < 2; ++sp)
          afrg[sp] = *(const bf16x8*)&Fs[((w * 2 + sp) * 16 + r) * 104 + kb * 32 + q * 8];
#pragma unroll
        for (int nt = 0; nt < 6; ++nt) {
          bf16x8 bfrg = *(const bf16x8*)&Ws[(kb * 96 + nt * 16 + r) * 32 + psw * 8];
#pragma unroll
          for (int sp = 0; sp < 2; ++sp)
            acc3[sp][nt] = __builtin_amdgcn_mfma_f32_16x16x32_bf16(
                afrg[sp], bfrg, acc3[sp][nt], 0, 0, 0);
        }
      }
    }

    // ---- chunk pooling: online softmax accumulate ----
    // C-layout: h = nt*16 + r, s_local = (w*2+sp)*16 + q*4 + rg
#pragma unroll
    for (int nt = 0; nt < 6; ++nt) {
      const int h = nt * 16 + r;
      const float b2v = b2s[h];
      float lm = -3e30f;
#pragma unroll
      for (int sp = 0; sp < 2; ++sp) {
#pragma unroll
        for (int rg = 0; rg < 4; ++rg) {
          const int sl = (w * 2 + sp) * 16 + q * 4 + rg;
          float lg = acc3[sp][nt][rg] + b2v + bias_s[c * 128 + sl];
          lm = fmaxf(lm, lg);
        }
      }
      lm = fmaxf(lm, __shfl_xor(lm, 16));
      lm = fmaxf(lm, __shfl_xor(lm, 32));
      if (q == 0) redA[w][h] = lm;
    }
    __syncthreads();  // chunk-max ready across waves
#pragma unroll
    for (int nt = 0; nt < 6; ++nt) {
      const int h = nt * 16 + r;
      // swizzled Ys scalar read setup: element-h granule
      const int gh = nt * 2 + (r >> 3);
      const int kbh = gh >> 2, ph_ = gh & 3;
      const int hlo = r & 7;
      const float cm = fmaxf(fmaxf(redA[0][h], redA[1][h]),
                             fmaxf(redA[2][h], redA[3][h]));
      const float mnew = fmaxf(m_run[nt], cm);
      const float sc = __expf(m_run[nt] - mnew);
      m_run[nt] = mnew;
      float lacc = l_run[nt] * sc;
      float vacc = v_run[nt] * sc;
      const float b2v = b2s[h];
#pragma unroll
      for (int sp = 0; sp < 2; ++sp) {
#pragma unroll
        for (int rg = 0; rg < 4; ++rg) {
          const int sl = (w * 2 + sp) * 16 + q * 4 + rg;
          float lg = acc3[sp][nt][rg] + b2v + bias_s[c * 128 + sl];
          float e = __expf(lg - mnew);
          lacc += e;
          const int pos = ph_ ^ ((sl >> 1) & 3);
          vacc += e * bf16_to_f32(Ys[sl * 96 + kbh * 32 + pos * 8 + hlo]);
        }
      }
      l_run[nt] = lacc;
      v_run[nt] = vacc;
    }
  }

  // ---- final reduce: sum l,v across q-groups then waves; out = v/l ----
  __syncthreads();  // redA/redB free
#pragma unroll
  for (int nt = 0; nt < 6; ++nt) {
    float ls = l_run[nt], vs = v_run[nt];
    ls += __shfl_xor(ls, 16);
    vs += __shfl_xor(vs, 16);
    ls += __shfl_xor(ls, 32);
    vs += __shfl_xor(vs, 32);
    if (q == 0) {
      redA[w][nt * 16 + r] = ls;
      redB[w][nt * 16 + r] = vs;
    }
  }
  __syncthreads();
  if (tid < 96) {
    float ls = redA[0][tid] + redA[1][tid] + redA[2][tid] + redA[3][tid];
    float vs = redB[0][tid] + redB[1][tid] + redB[2][tid] + redB[3][tid];
    out[(size_t)b * 768 + hd * 96 + tid] = vs / ls;
  }
}

// ---------------- launcher ----------------

extern "C" void kernel_launch(void* const* d_in, const int* in_sizes, int n_in,
                              void* d_out, int out_size, void* d_ws, size_t ws_size,
                              hipStream_t stream) {
  const float* X    = (const float*)d_in[0];
  const float* mask = (const float*)d_in[1];
  const float* P    = (const float*)d_in[2];
  const float* bP   = (const float*)d_in[3];
  const float* W1   = (const float*)d_in[4];
  const float* b1   = (const float*)d_in[5];
  const float* W2   = (const float*)d_in[6];
  const float* b2   = (const float*)d_in[7];
  float* out = (float*)d_out;
  (void)in_sizes; (void)n_in; (void)out_size; (void)ws_size;

  unsigned short* Xbf  = (unsigned short*)d_ws;
  unsigned short* Pbf  = Xbf + N_X;
  unsigned short* W1bf = Pbf + N_P;
  unsigned short* W2bf = W1bf + N_W1;
  unsigned short* Hi   = W2bf + N_W2;

  cast_f32_bf16<<<N_X / 4 / 256, 256, 0, stream>>>(X, Xbf, N_X / 4);
  cast_f32_bf16<<<N_P / 4 / 256, 256, 0, stream>>>(P, Pbf, N_P / 4);
  cast_f32_bf16<<<N_W1 / 4 / 256, 256, 0, stream>>>(W1, W1bf, N_W1 / 4);
  cast_f32_bf16<<<N_W2 / 4 / 256, 256, 0, stream>>>(W2, W2bf, N_W2 / 4);

  gemm_hi<<<dim3(6, 512), 256, 0, stream>>>(Xbf, Pbf, bP, Hi);
  mlp_pool<<<8 * 128, 256, 0, stream>>>(Hi, W1bf, W2bf, b1, b2, mask, out);
}

// Round 4
// 525.364 us; speedup vs baseline: 1.0807x; 1.0448x over previous
//
#include <hip/hip_runtime.h>
#include <stdint.h>

// ---------------- common types / helpers ----------------

typedef short bf16x8 __attribute__((ext_vector_type(8)));
typedef float f32x4 __attribute__((ext_vector_type(4)));

struct alignas(8) us4 { unsigned short x, y, z, w; };

__device__ __forceinline__ unsigned short f32_to_bf16(float f) {
  union { float f; uint32_t u; } v; v.f = f;
  uint32_t u = v.u;
  uint32_t r = (u + 0x7fffu + ((u >> 16) & 1u)) >> 16;  // RNE
  return (unsigned short)r;
}

__device__ __forceinline__ float bf16_to_f32(unsigned short h) {
  union { uint32_t u; float f; } v; v.u = ((uint32_t)h) << 16;
  return v.f;
}

// pack two f32 into bf16x2 by truncation: one v_perm_b32
__device__ __forceinline__ uint32_t pack_bf16_trunc(float lo, float hi) {
  union { float f; uint32_t u; } a, b; a.f = lo; b.f = hi;
  return __builtin_amdgcn_perm(b.u, a.u, 0x07060302u);  // [lo.hi16, hi.hi16]
}

// async global->LDS, 16B per lane; LDS dest is wave-uniform base + lane*16
__device__ __forceinline__ void g2l16(const unsigned short* g, unsigned short* l) {
  __builtin_amdgcn_global_load_lds((__attribute__((address_space(1))) void*)g,
                                   (__attribute__((address_space(3))) void*)l,
                                   16, 0, 0);
}

// ---------------- problem constants ----------------
// B=128, S=512, D=768, NH=8, HD=96, HID=384

#define N_X   50331648   // 128*512*768
#define N_P   589824     // 8*96*768
#define N_W1  294912     // 8*384*96
#define N_W2  294912     // 8*96*384
#define N_HI  50331648   // 8*128*512*96  (plane-blocked: [hd*128+b][kb][s][32])

// ---------------- kernel 0: fp32 -> bf16 cast (X, P only) ----------------

__global__ __launch_bounds__(256) void cast_f32_bf16(
    const float* __restrict__ src, unsigned short* __restrict__ dst, int n4) {
  int idx = blockIdx.x * 256 + threadIdx.x;
  if (idx >= n4) return;
  float4 v = ((const float4*)src)[idx];
  us4 o;
  o.x = f32_to_bf16(v.x);
  o.y = f32_to_bf16(v.y);
  o.z = f32_to_bf16(v.z);
  o.w = f32_to_bf16(v.w);
  ((us4*)dst)[idx] = o;
}

// ---------------- repack kernels: cast + pre-swizzle weights ----------------
// Output = exact LDS image per (hd,ph) quarter: [kb][row][32], where slot s of
// row holds source granule s ^ ((row>>1)&3). mlp_pool then stages LINEARLY.

__global__ __launch_bounds__(256) void repack_w1(
    const float* __restrict__ W1, unsigned short* __restrict__ W1bf) {
  const int quarter = blockIdx.x;  // hd*4 + ph, 32 blocks
  const int hd = quarter >> 2, ph = quarter & 3;
  for (int t = threadIdx.x; t < 1152; t += 256) {
    const int kb = t / 384;
    const int rem = t - kb * 384;
    const int f = rem >> 2, slot = rem & 3;
    const int pos = slot ^ ((f >> 1) & 3);
    const float* src =
        W1 + ((size_t)(hd * 384 + ph * 96 + f)) * 96 + kb * 32 + pos * 8;
    float4 a = *(const float4*)src;
    float4 b = *(const float4*)(src + 4);
    us4 o1 = {f32_to_bf16(a.x), f32_to_bf16(a.y), f32_to_bf16(a.z), f32_to_bf16(a.w)};
    us4 o2 = {f32_to_bf16(b.x), f32_to_bf16(b.y), f32_to_bf16(b.z), f32_to_bf16(b.w)};
    us4* dst = (us4*)(W1bf + (size_t)quarter * 9216 + t * 8);
    dst[0] = o1;
    dst[1] = o2;
  }
}

__global__ __launch_bounds__(256) void repack_w2(
    const float* __restrict__ W2, unsigned short* __restrict__ W2bf) {
  const int quarter = blockIdx.x;  // hd*4 + ph
  const int hd = quarter >> 2, ph = quarter & 3;
  for (int t = threadIdx.x; t < 1152; t += 256) {
    const int kb = t / 384;
    const int rem = t - kb * 384;
    const int h = rem >> 2, slot = rem & 3;
    const int pos = slot ^ ((h >> 1) & 3);
    const float* src =
        W2 + ((size_t)(hd * 96 + h)) * 384 + ph * 96 + kb * 32 + pos * 8;
    float4 a = *(const float4*)src;
    float4 b = *(const float4*)(src + 4);
    us4 o1 = {f32_to_bf16(a.x), f32_to_bf16(a.y), f32_to_bf16(a.z), f32_to_bf16(a.w)};
    us4 o2 = {f32_to_bf16(b.x), f32_to_bf16(b.y), f32_to_bf16(b.z), f32_to_bf16(b.w)};
    us4* dst = (us4*)(W2bf + (size_t)quarter * 9216 + t * 8);
    dst[0] = o1;
    dst[1] = o2;
  }
}

// ---------------- kernel 1: Hi = X @ P^T + bP (plane-blocked output) ----------------
// As/Bs granule swizzle via pre-swizzled sources (cheap shift/mask math).
// Epilogue writes Hi in plane-blocked layout: [hd*128+b][kb=h>>5][s][h&31].

__global__ __launch_bounds__(256) void gemm_hi(
    const unsigned short* __restrict__ Xbf,
    const unsigned short* __restrict__ Pbf,
    const float* __restrict__ bP,
    unsigned short* __restrict__ Hi) {
  __shared__ __align__(16) unsigned short As[128 * 32];
  __shared__ __align__(16) unsigned short Bs[128 * 32];

  const int tid = threadIdx.x;
  const int w = tid >> 6;
  const int lane = tid & 63;
  const int r = lane & 15;
  const int q = lane >> 4;
  const int bn = blockIdx.x;  // 0..5
  const int bm = blockIdx.y;  // 0..511
  const int wr = w >> 1, wc = w & 1;
  const int psw = q ^ ((r >> 1) & 3);  // swizzled read granule

  f32x4 acc[4][4];
#pragma unroll
  for (int a = 0; a < 4; ++a)
#pragma unroll
    for (int c = 0; c < 4; ++c) acc[a][c] = (f32x4){0.f, 0.f, 0.f, 0.f};

  const int ldr = lane >> 2;
  // source granule = (lane&3) ^ ((row_d>>1)&3); row_d = w*16 + ldr -> (ldr>>1)&3
  const int ldc = ((lane & 3) ^ ((lane >> 3) & 3)) * 8;
  const unsigned short* Abase = Xbf + (size_t)(bm * 128) * 768 + ldc;
  const unsigned short* Bbase = Pbf + (size_t)(bn * 128) * 768 + ldc;

  for (int k0 = 0; k0 < 768; k0 += 32) {
    __syncthreads();
    g2l16(Abase + (size_t)(w * 16 + ldr) * 768 + k0, &As[w * 512]);
    g2l16(Abase + (size_t)(64 + w * 16 + ldr) * 768 + k0, &As[(4 + w) * 512]);
    g2l16(Bbase + (size_t)(w * 16 + ldr) * 768 + k0, &Bs[w * 512]);
    g2l16(Bbase + (size_t)(64 + w * 16 + ldr) * 768 + k0, &Bs[(4 + w) * 512]);
    __syncthreads();

    bf16x8 af[4], bfr[4];
#pragma unroll
    for (int t = 0; t < 4; ++t)
      af[t] = *(const bf16x8*)&As[(wr * 64 + t * 16 + r) * 32 + psw * 8];
#pragma unroll
    for (int t = 0; t < 4; ++t)
      bfr[t] = *(const bf16x8*)&Bs[(wc * 64 + t * 16 + r) * 32 + psw * 8];
#pragma unroll
    for (int mt = 0; mt < 4; ++mt)
#pragma unroll
      for (int nt = 0; nt < 4; ++nt)
        acc[mt][nt] = __builtin_amdgcn_mfma_f32_16x16x32_bf16(
            af[mt], bfr[nt], acc[mt][nt], 0, 0, 0);
  }

  const int bb = bm >> 2;
  const int sb = (bm & 3) * 128 + wr * 64;
#pragma unroll
  for (int nt = 0; nt < 4; ++nt) {
    const int n0 = bn * 128 + wc * 64 + nt * 16;
    const int hd = n0 / 96;
    const int hloc = n0 - hd * 96;       // multiple of 16
    const int kb = hloc >> 5;            // plane, const per nt
    const int col = (hloc & 31) + r;     // within-plane column
    const float bias = bP[n0 + r];
    unsigned short* obase =
        Hi + (size_t)(hd * 128 + bb) * 49152 + kb * 16384 + col;
#pragma unroll
    for (int mt = 0; mt < 4; ++mt) {
#pragma unroll
      for (int rg = 0; rg < 4; ++rg) {
        const int s = sb + mt * 16 + q * 4 + rg;
        obase[(size_t)s * 32] = f32_to_bf16(acc[mt][nt][rg] + bias);
      }
    }
  }
}

// ---------------- kernel 2: fused per-head MLP -> logits -> softmax -> pool ----------------
// v5 = R1 phase structure + swizzled LDS images, with ALL swizzle address math
// removed from the kernel:
//  * W1/W2 staged LINEARLY from pre-swizzled repack images ([kb][row][32]).
//  * Ys staged from plane-blocked Hi; per-thread source offset is one XOR
//    (wl ^ ((wl>>3)&3))*8 -- the within-64B granule permutation.
//  * Fragment reads use psw = q ^ ((r>>1)&3); pooling scalar reads use the
//    plane-layout inverse. Content verified: slot psw holds source granule q.
// (R3 lesson: /12 & /384 per-g2l16 address math got hoisted -> 16 live VGPRs
//  -> spill: WRITE_SIZE 27MB. This version has R1's register footprint.)
// LDS ~74.7 KB -> 2 blocks/CU.

__global__ __launch_bounds__(256, 2) void mlp_pool(
    const unsigned short* __restrict__ Hi,    // plane-blocked
    const unsigned short* __restrict__ W1bf,  // [(hd,ph)][kb][f][32] pre-swizzled
    const unsigned short* __restrict__ W2bf,  // [(hd,ph)][kb][h][32] pre-swizzled
    const float* __restrict__ b1,             // 8*384
    const float* __restrict__ b2,             // 8*96
    const float* __restrict__ mask,           // B x S
    float* __restrict__ out) {                // B x 768
  __shared__ __align__(16) unsigned short Ys[3 * 128 * 32];  // [kb][s][32] swizzled
  __shared__ __align__(16) unsigned short Ws[3 * 96 * 32];   // W1q/W2q [kb][row][32] swizzled
  __shared__ __align__(16) unsigned short Fs[128 * 104];     // [s][96 + 8 pad]
  __shared__ __align__(16) float b1s[384];
  __shared__ __align__(16) float b2s[96];
  __shared__ float bias_s[512];
  __shared__ float redA[4][96];
  __shared__ float redB[4][96];

  const int x = blockIdx.x;
  const int b = x & 127;    // batch
  const int hd = x >> 7;    // head (slowest -> weight L2 sharing)

  const int tid = threadIdx.x;
  const int w = tid >> 6;
  const int lane = tid & 63;
  const int r = lane & 15;
  const int q = lane >> 4;
  const int psw = q ^ ((r >> 1) & 3);  // swizzled read granule
  // per-thread Ys source offset: granule permutation within each 64B third
  const int ysx = (tid ^ ((tid >> 3) & 3)) * 8;

  if (tid < 96) b2s[tid] = b2[hd * 96 + tid];
  for (int i = tid; i < 384; i += 256) b1s[i] = b1[hd * 384 + i];
  for (int s = tid; s < 512; s += 256)
    bias_s[s] = mask[b * 512 + s] > 0.5f ? 0.f : -1e30f;

  float m_run[6], l_run[6], v_run[6];
#pragma unroll
  for (int nt = 0; nt < 6; ++nt) { m_run[nt] = -3e30f; l_run[nt] = 0.f; v_run[nt] = 0.f; }

  const unsigned short* ysrc = Hi + (size_t)(hd * 128 + b) * 49152;

  for (int c = 0; c < 4; ++c) {
    __syncthreads();  // prev pooling done reading Ys/redA; prev GEMM3 done with Ws/Fs

    // stage Y chunk: 3 planes x 512 granules, linear dest, source = plane base
    // + c*4096 + per-it const + per-thread permuted offset (shorts)
    {
      const unsigned short* yc = ysrc + c * 4096 + ysx;
      g2l16(yc, &Ys[w * 512]);                    // it=0: plane0 rows 0..63
      g2l16(yc + 2048, &Ys[(4 + w) * 512]);       // it=1: plane0 rows 64..127
      g2l16(yc + 16384, &Ys[(8 + w) * 512]);      // it=2: plane1 lo
      g2l16(yc + 18432, &Ys[(12 + w) * 512]);     // it=3: plane1 hi
      g2l16(yc + 32768, &Ys[(16 + w) * 512]);     // it=4: plane2 lo
      g2l16(yc + 34816, &Ys[(20 + w) * 512]);     // it=5: plane2 hi
    }

    f32x4 acc3[2][6];
#pragma unroll
    for (int sp = 0; sp < 2; ++sp)
#pragma unroll
      for (int nt = 0; nt < 6; ++nt) acc3[sp][nt] = (f32x4){0.f, 0.f, 0.f, 0.f};

    for (int ph = 0; ph < 4; ++ph) {
      if (ph) __syncthreads();  // GEMM3(ph-1) done reading Ws/Fs

      // stage W1 quarter: LINEAR copy of pre-swizzled image (1152 granules)
      const unsigned short* w1src = W1bf + (size_t)(hd * 4 + ph) * 9216;
#pragma unroll
      for (int it = 0; it < 4; ++it)
        g2l16(w1src + (size_t)((it * 4 + w) * 64 + lane) * 8, &Ws[(it * 4 + w) * 512]);
      if (w < 2)
        g2l16(w1src + (size_t)((16 + w) * 64 + lane) * 8, &Ws[(16 + w) * 512]);
      __syncthreads();  // W1q ready (and Ys on ph==0)

      // GEMM2: F^T = W1q @ Y^T. M=96(f), N=128(s), K=96.
      f32x4 acc2[6][2];
#pragma unroll
      for (int ft = 0; ft < 6; ++ft)
#pragma unroll
        for (int sp = 0; sp < 2; ++sp) acc2[ft][sp] = (f32x4){0.f, 0.f, 0.f, 0.f};
#pragma unroll
      for (int kb = 0; kb < 3; ++kb) {
        bf16x8 bfrg[2];
#pragma unroll
        for (int sp = 0; sp < 2; ++sp)
          bfrg[sp] = *(const bf16x8*)&Ys[kb * 4096 + ((w * 2 + sp) * 16 + r) * 32 + psw * 8];
#pragma unroll
        for (int ft = 0; ft < 6; ++ft) {
          bf16x8 afrg = *(const bf16x8*)&Ws[kb * 3072 + (ft * 16 + r) * 32 + psw * 8];
#pragma unroll
          for (int sp = 0; sp < 2; ++sp)
            acc2[ft][sp] = __builtin_amdgcn_mfma_f32_16x16x32_bf16(
                afrg, bfrg[sp], acc2[ft][sp], 0, 0, 0);
        }
      }
      // epilogue: +b1, relu, pack pairs, b64 write to Fs ([s][104], pad layout)
#pragma unroll
      for (int ft = 0; ft < 6; ++ft) {
        float4 bv = *(const float4*)&b1s[ph * 96 + ft * 16 + q * 4];
#pragma unroll
        for (int sp = 0; sp < 2; ++sp) {
          const int s = (w * 2 + sp) * 16 + r;
          float v0 = fmaxf(acc2[ft][sp][0] + bv.x, 0.f);
          float v1 = fmaxf(acc2[ft][sp][1] + bv.y, 0.f);
          float v2 = fmaxf(acc2[ft][sp][2] + bv.z, 0.f);
          float v3 = fmaxf(acc2[ft][sp][3] + bv.w, 0.f);
          uint2 pk;
          pk.x = pack_bf16_trunc(v0, v1);
          pk.y = pack_bf16_trunc(v2, v3);
          *(uint2*)((uint32_t*)&Fs[0] + s * 52 + ft * 8 + q * 2) = pk;
        }
      }
      __syncthreads();  // Fs ready; Ws (W1q) consumed

      // stage W2 quarter: LINEAR copy of pre-swizzled image
      const unsigned short* w2src = W2bf + (size_t)(hd * 4 + ph) * 9216;
#pragma unroll
      for (int it = 0; it < 4; ++it)
        g2l16(w2src + (size_t)((it * 4 + w) * 64 + lane) * 8, &Ws[(it * 4 + w) * 512]);
      if (w < 2)
        g2l16(w2src + (size_t)((16 + w) * 64 + lane) * 8, &Ws[(16 + w) * 512]);
      __syncthreads();  // Ws(W2q) ready

      // GEMM3 partial: M=128(s), N=96(h), K=96 this phase.
#pragma unroll
      for (int kb = 0; kb < 3; ++kb) {
        bf16x8 afrg[2];
#pragma unroll
        for (int sp = 0; sp < 2; ++sp)
          afrg[sp] = *(const bf16x8*)&Fs[((w * 2 + sp) * 16 + r) * 104 + kb * 32 + q * 8];
#pragma unroll
        for (int nt = 0; nt < 6; ++nt) {
          bf16x8 bfrg = *(const bf16x8*)&Ws[kb * 3072 + (nt * 16 + r) * 32 + psw * 8];
#pragma unroll
          for (int sp = 0; sp < 2; ++sp)
            acc3[sp][nt] = __builtin_amdgcn_mfma_f32_16x16x32_bf16(
                afrg[sp], bfrg, acc3[sp][nt], 0, 0, 0);
        }
      }
    }

    // ---- chunk pooling: online softmax accumulate ----
    // C-layout: h = nt*16 + r, s_local = (w*2+sp)*16 + q*4 + rg
#pragma unroll
    for (int nt = 0; nt < 6; ++nt) {
      const float b2v = b2s[nt * 16 + r];
      float lm = -3e30f;
#pragma unroll
      for (int sp = 0; sp < 2; ++sp) {
#pragma unroll
        for (int rg = 0; rg < 4; ++rg) {
          const int sl = (w * 2 + sp) * 16 + q * 4 + rg;
          float lg = acc3[sp][nt][rg] + b2v + bias_s[c * 128 + sl];
          lm = fmaxf(lm, lg);
        }
      }
      lm = fmaxf(lm, __shfl_xor(lm, 16));
      lm = fmaxf(lm, __shfl_xor(lm, 32));
      if (q == 0) redA[w][nt * 16 + r] = lm;
    }
    __syncthreads();  // chunk-max ready across waves
#pragma unroll
    for (int nt = 0; nt < 6; ++nt) {
      const int h = nt * 16 + r;
      // plane-layout swizzled Ys scalar read setup
      const int kbh = nt >> 1;                  // h>>5
      const int gh = (nt * 2 + (r >> 3)) & 3;   // (h>>3)&3
      const int hlo = r & 7;
      const float cm = fmaxf(fmaxf(redA[0][h], redA[1][h]),
                             fmaxf(redA[2][h], redA[3][h]));
      const float mnew = fmaxf(m_run[nt], cm);
      const float sc = __expf(m_run[nt] - mnew);
      m_run[nt] = mnew;
      float lacc = l_run[nt] * sc;
      float vacc = v_run[nt] * sc;
      const float b2v = b2s[h];
#pragma unroll
      for (int sp = 0; sp < 2; ++sp) {
#pragma unroll
        for (int rg = 0; rg < 4; ++rg) {
          const int sl = (w * 2 + sp) * 16 + q * 4 + rg;
          float lg = acc3[sp][nt][rg] + b2v + bias_s[c * 128 + sl];
          float e = __expf(lg - mnew);
          lacc += e;
          const int pos = gh ^ ((sl >> 1) & 3);
          vacc += e * bf16_to_f32(Ys[kbh * 4096 + sl * 32 + pos * 8 + hlo]);
        }
      }
      l_run[nt] = lacc;
      v_run[nt] = vacc;
    }
  }

  // ---- final reduce: sum l,v across q-groups then waves; out = v/l ----
  __syncthreads();  // redA/redB free
#pragma unroll
  for (int nt = 0; nt < 6; ++nt) {
    float ls = l_run[nt], vs = v_run[nt];
    ls += __shfl_xor(ls, 16);
    vs += __shfl_xor(vs, 16);
    ls += __shfl_xor(ls, 32);
    vs += __shfl_xor(vs, 32);
    if (q == 0) {
      redA[w][nt * 16 + r] = ls;
      redB[w][nt * 16 + r] = vs;
    }
  }
  __syncthreads();
  if (tid < 96) {
    float ls = redA[0][tid] + redA[1][tid] + redA[2][tid] + redA[3][tid];
    float vs = redB[0][tid] + redB[1][tid] + redB[2][tid] + redB[3][tid];
    out[(size_t)b * 768 + hd * 96 + tid] = vs / ls;
  }
}

// ---------------- launcher ----------------

extern "C" void kernel_launch(void* const* d_in, const int* in_sizes, int n_in,
                              void* d_out, int out_size, void* d_ws, size_t ws_size,
                              hipStream_t stream) {
  const float* X    = (const float*)d_in[0];
  const float* mask = (const float*)d_in[1];
  const float* P    = (const float*)d_in[2];
  const float* bP   = (const float*)d_in[3];
  const float* W1   = (const float*)d_in[4];
  const float* b1   = (const float*)d_in[5];
  const float* W2   = (const float*)d_in[6];
  const float* b2   = (const float*)d_in[7];
  float* out = (float*)d_out;
  (void)in_sizes; (void)n_in; (void)out_size; (void)ws_size;

  unsigned short* Xbf  = (unsigned short*)d_ws;
  unsigned short* Pbf  = Xbf + N_X;
  unsigned short* W1bf = Pbf + N_P;
  unsigned short* W2bf = W1bf + N_W1;
  unsigned short* Hi   = W2bf + N_W2;

  cast_f32_bf16<<<N_X / 4 / 256, 256, 0, stream>>>(X, Xbf, N_X / 4);
  cast_f32_bf16<<<N_P / 4 / 256, 256, 0, stream>>>(P, Pbf, N_P / 4);
  repack_w1<<<32, 256, 0, stream>>>(W1, W1bf);
  repack_w2<<<32, 256, 0, stream>>>(W2, W2bf);

  gemm_hi<<<dim3(6, 512), 256, 0, stream>>>(Xbf, Pbf, bP, Hi);
  mlp_pool<<<8 * 128, 256, 0, stream>>>(Hi, W1bf, W2bf, b1, b2, mask, out);
}

// Round 5
// 519.734 us; speedup vs baseline: 1.0924x; 1.0108x over previous
//
#include <hip/hip_runtime.h>
#include <stdint.h>

// ---------------- common types / helpers ----------------

typedef short bf16x8 __attribute__((ext_vector_type(8)));
typedef float f32x4 __attribute__((ext_vector_type(4)));

struct alignas(8) us4 { unsigned short x, y, z, w; };

__device__ __forceinline__ unsigned short f32_to_bf16(float f) {
  union { float f; uint32_t u; } v; v.f = f;
  uint32_t u = v.u;
  uint32_t r = (u + 0x7fffu + ((u >> 16) & 1u)) >> 16;  // RNE
  return (unsigned short)r;
}

__device__ __forceinline__ float bf16_to_f32(unsigned short h) {
  union { uint32_t u; float f; } v; v.u = ((uint32_t)h) << 16;
  return v.f;
}

// pack two f32 into bf16x2 by truncation: one v_perm_b32
__device__ __forceinline__ uint32_t pack_bf16_trunc(float lo, float hi) {
  union { float f; uint32_t u; } a, b; a.f = lo; b.f = hi;
  return __builtin_amdgcn_perm(b.u, a.u, 0x07060302u);  // [lo.hi16, hi.hi16]
}

// async global->LDS, 16B per lane; LDS dest is wave-uniform base + lane*16
__device__ __forceinline__ void g2l16(const unsigned short* g, unsigned short* l) {
  __builtin_amdgcn_global_load_lds((__attribute__((address_space(1))) void*)g,
                                   (__attribute__((address_space(3))) void*)l,
                                   16, 0, 0);
}

// ---------------- problem constants ----------------
// B=128, S=512, D=768, NH=8, HD=96, HID=384

#define N_X   50331648   // 128*512*768
#define N_P   589824     // 8*96*768
#define N_W1  294912     // 8*384*96
#define N_W2  294912     // 8*96*384
#define N_HI  50331648   // 8*128*512*96  (plane-blocked: [hd*128+b][kb][s][32])

// ---------------- kernel 0: fp32 -> bf16 cast (X, P only) ----------------

__global__ __launch_bounds__(256) void cast_f32_bf16(
    const float* __restrict__ src, unsigned short* __restrict__ dst, int n4) {
  int idx = blockIdx.x * 256 + threadIdx.x;
  if (idx >= n4) return;
  float4 v = ((const float4*)src)[idx];
  us4 o;
  o.x = f32_to_bf16(v.x);
  o.y = f32_to_bf16(v.y);
  o.z = f32_to_bf16(v.z);
  o.w = f32_to_bf16(v.w);
  ((us4*)dst)[idx] = o;
}

// ---------------- repack kernels: cast + pre-swizzle weights ----------------
// Output = exact LDS image per (hd,ph) quarter: [kb][row][32], where slot s of
// row holds source granule s ^ ((row>>1)&3). mlp_pool then stages LINEARLY.

__global__ __launch_bounds__(256) void repack_w1(
    const float* __restrict__ W1, unsigned short* __restrict__ W1bf) {
  const int quarter = blockIdx.x;  // hd*4 + ph, 32 blocks
  const int hd = quarter >> 2, ph = quarter & 3;
  for (int t = threadIdx.x; t < 1152; t += 256) {
    const int kb = t / 384;
    const int rem = t - kb * 384;
    const int f = rem >> 2, slot = rem & 3;
    const int pos = slot ^ ((f >> 1) & 3);
    const float* src =
        W1 + ((size_t)(hd * 384 + ph * 96 + f)) * 96 + kb * 32 + pos * 8;
    float4 a = *(const float4*)src;
    float4 b = *(const float4*)(src + 4);
    us4 o1 = {f32_to_bf16(a.x), f32_to_bf16(a.y), f32_to_bf16(a.z), f32_to_bf16(a.w)};
    us4 o2 = {f32_to_bf16(b.x), f32_to_bf16(b.y), f32_to_bf16(b.z), f32_to_bf16(b.w)};
    us4* dst = (us4*)(W1bf + (size_t)quarter * 9216 + t * 8);
    dst[0] = o1;
    dst[1] = o2;
  }
}

__global__ __launch_bounds__(256) void repack_w2(
    const float* __restrict__ W2, unsigned short* __restrict__ W2bf) {
  const int quarter = blockIdx.x;  // hd*4 + ph
  const int hd = quarter >> 2, ph = quarter & 3;
  for (int t = threadIdx.x; t < 1152; t += 256) {
    const int kb = t / 384;
    const int rem = t - kb * 384;
    const int h = rem >> 2, slot = rem & 3;
    const int pos = slot ^ ((h >> 1) & 3);
    const float* src =
        W2 + ((size_t)(hd * 96 + h)) * 384 + ph * 96 + kb * 32 + pos * 8;
    float4 a = *(const float4*)src;
    float4 b = *(const float4*)(src + 4);
    us4 o1 = {f32_to_bf16(a.x), f32_to_bf16(a.y), f32_to_bf16(a.z), f32_to_bf16(a.w)};
    us4 o2 = {f32_to_bf16(b.x), f32_to_bf16(b.y), f32_to_bf16(b.z), f32_to_bf16(b.w)};
    us4* dst = (us4*)(W2bf + (size_t)quarter * 9216 + t * 8);
    dst[0] = o1;
    dst[1] = o2;
  }
}

// ---------------- kernel 1: Hi = X @ P^T + bP (plane-blocked output) ----------------
// v6: XCD-aware block remap. Grid is 1D 3072 = 8 XCDs x 384. The 6 blocks
// sharing an X-slice (same bm, bn=0..5) had consecutive linear ids -> landed
// on 6 DIFFERENT XCDs -> 6x private-L2 X re-fetch (measured FETCH=306MB = 3x
// ideal after L3 help). Remap wkid = (hwid%8)*384 + hwid/8 gives each XCD a
// contiguous bm range [64x, 64x+64) with all bn -> X fetched ~once per XCD.
// 3072 % 8 == 0 -> bijective.

__global__ __launch_bounds__(256) void gemm_hi(
    const unsigned short* __restrict__ Xbf,
    const unsigned short* __restrict__ Pbf,
    const float* __restrict__ bP,
    unsigned short* __restrict__ Hi) {
  __shared__ __align__(16) unsigned short As[128 * 32];
  __shared__ __align__(16) unsigned short Bs[128 * 32];

  const int tid = threadIdx.x;
  const int w = tid >> 6;
  const int lane = tid & 63;
  const int r = lane & 15;
  const int q = lane >> 4;

  // XCD-aware remap (T1): hwid -> wkid -> (bn fastest, bm)
  const int hwid = blockIdx.x;                      // 0..3071
  const int wkid = (hwid & 7) * 384 + (hwid >> 3);  // per-XCD contiguous chunk
  const int bn = wkid % 6;   // 0..5
  const int bm = wkid / 6;   // 0..511 ; XCD x covers bm in [64x, 64x+64)

  const int wr = w >> 1, wc = w & 1;
  const int psw = q ^ ((r >> 1) & 3);  // swizzled read granule

  f32x4 acc[4][4];
#pragma unroll
  for (int a = 0; a < 4; ++a)
#pragma unroll
    for (int c = 0; c < 4; ++c) acc[a][c] = (f32x4){0.f, 0.f, 0.f, 0.f};

  const int ldr = lane >> 2;
  // source granule = (lane&3) ^ ((row_d>>1)&3); row_d = w*16 + ldr -> (ldr>>1)&3
  const int ldc = ((lane & 3) ^ ((lane >> 3) & 3)) * 8;
  const unsigned short* Abase = Xbf + (size_t)(bm * 128) * 768 + ldc;
  const unsigned short* Bbase = Pbf + (size_t)(bn * 128) * 768 + ldc;

  for (int k0 = 0; k0 < 768; k0 += 32) {
    __syncthreads();
    g2l16(Abase + (size_t)(w * 16 + ldr) * 768 + k0, &As[w * 512]);
    g2l16(Abase + (size_t)(64 + w * 16 + ldr) * 768 + k0, &As[(4 + w) * 512]);
    g2l16(Bbase + (size_t)(w * 16 + ldr) * 768 + k0, &Bs[w * 512]);
    g2l16(Bbase + (size_t)(64 + w * 16 + ldr) * 768 + k0, &Bs[(4 + w) * 512]);
    __syncthreads();

    bf16x8 af[4], bfr[4];
#pragma unroll
    for (int t = 0; t < 4; ++t)
      af[t] = *(const bf16x8*)&As[(wr * 64 + t * 16 + r) * 32 + psw * 8];
#pragma unroll
    for (int t = 0; t < 4; ++t)
      bfr[t] = *(const bf16x8*)&Bs[(wc * 64 + t * 16 + r) * 32 + psw * 8];
#pragma unroll
    for (int mt = 0; mt < 4; ++mt)
#pragma unroll
      for (int nt = 0; nt < 4; ++nt)
        acc[mt][nt] = __builtin_amdgcn_mfma_f32_16x16x32_bf16(
            af[mt], bfr[nt], acc[mt][nt], 0, 0, 0);
  }

  const int bb = bm >> 2;
  const int sb = (bm & 3) * 128 + wr * 64;
#pragma unroll
  for (int nt = 0; nt < 4; ++nt) {
    const int n0 = bn * 128 + wc * 64 + nt * 16;
    const int hd = n0 / 96;
    const int hloc = n0 - hd * 96;       // multiple of 16
    const int kb = hloc >> 5;            // plane, const per nt
    const int col = (hloc & 31) + r;     // within-plane column
    const float bias = bP[n0 + r];
    unsigned short* obase =
        Hi + (size_t)(hd * 128 + bb) * 49152 + kb * 16384 + col;
#pragma unroll
    for (int mt = 0; mt < 4; ++mt) {
#pragma unroll
      for (int rg = 0; rg < 4; ++rg) {
        const int s = sb + mt * 16 + q * 4 + rg;
        obase[(size_t)s * 32] = f32_to_bf16(acc[mt][nt][rg] + bias);
      }
    }
  }
}

// ---------------- kernel 2: fused per-head MLP -> logits -> softmax -> pool ----------------
// (unchanged from R4: R1 phase structure + pre-swizzled LDS images, linear
//  staging, zero in-kernel swizzle math. 128.2us, WRITE=384KB, VGPR 128.)
// LDS ~74.7 KB -> 2 blocks/CU.

__global__ __launch_bounds__(256, 2) void mlp_pool(
    const unsigned short* __restrict__ Hi,    // plane-blocked
    const unsigned short* __restrict__ W1bf,  // [(hd,ph)][kb][f][32] pre-swizzled
    const unsigned short* __restrict__ W2bf,  // [(hd,ph)][kb][h][32] pre-swizzled
    const float* __restrict__ b1,             // 8*384
    const float* __restrict__ b2,             // 8*96
    const float* __restrict__ mask,           // B x S
    float* __restrict__ out) {                // B x 768
  __shared__ __align__(16) unsigned short Ys[3 * 128 * 32];  // [kb][s][32] swizzled
  __shared__ __align__(16) unsigned short Ws[3 * 96 * 32];   // W1q/W2q [kb][row][32] swizzled
  __shared__ __align__(16) unsigned short Fs[128 * 104];     // [s][96 + 8 pad]
  __shared__ __align__(16) float b1s[384];
  __shared__ __align__(16) float b2s[96];
  __shared__ float bias_s[512];
  __shared__ float redA[4][96];
  __shared__ float redB[4][96];

  const int x = blockIdx.x;
  const int b = x & 127;    // batch
  const int hd = x >> 7;    // head (slowest -> weight L2 sharing)

  const int tid = threadIdx.x;
  const int w = tid >> 6;
  const int lane = tid & 63;
  const int r = lane & 15;
  const int q = lane >> 4;
  const int psw = q ^ ((r >> 1) & 3);  // swizzled read granule
  // per-thread Ys source offset: granule permutation within each 64B third
  const int ysx = (tid ^ ((tid >> 3) & 3)) * 8;

  if (tid < 96) b2s[tid] = b2[hd * 96 + tid];
  for (int i = tid; i < 384; i += 256) b1s[i] = b1[hd * 384 + i];
  for (int s = tid; s < 512; s += 256)
    bias_s[s] = mask[b * 512 + s] > 0.5f ? 0.f : -1e30f;

  float m_run[6], l_run[6], v_run[6];
#pragma unroll
  for (int nt = 0; nt < 6; ++nt) { m_run[nt] = -3e30f; l_run[nt] = 0.f; v_run[nt] = 0.f; }

  const unsigned short* ysrc = Hi + (size_t)(hd * 128 + b) * 49152;

  for (int c = 0; c < 4; ++c) {
    __syncthreads();  // prev pooling done reading Ys/redA; prev GEMM3 done with Ws/Fs

    // stage Y chunk: 3 planes x 512 granules, linear dest, source = plane base
    // + c*4096 + per-it const + per-thread permuted offset (shorts)
    {
      const unsigned short* yc = ysrc + c * 4096 + ysx;
      g2l16(yc, &Ys[w * 512]);                    // it=0: plane0 rows 0..63
      g2l16(yc + 2048, &Ys[(4 + w) * 512]);       // it=1: plane0 rows 64..127
      g2l16(yc + 16384, &Ys[(8 + w) * 512]);      // it=2: plane1 lo
      g2l16(yc + 18432, &Ys[(12 + w) * 512]);     // it=3: plane1 hi
      g2l16(yc + 32768, &Ys[(16 + w) * 512]);     // it=4: plane2 lo
      g2l16(yc + 34816, &Ys[(20 + w) * 512]);     // it=5: plane2 hi
    }

    f32x4 acc3[2][6];
#pragma unroll
    for (int sp = 0; sp < 2; ++sp)
#pragma unroll
      for (int nt = 0; nt < 6; ++nt) acc3[sp][nt] = (f32x4){0.f, 0.f, 0.f, 0.f};

    for (int ph = 0; ph < 4; ++ph) {
      if (ph) __syncthreads();  // GEMM3(ph-1) done reading Ws/Fs

      // stage W1 quarter: LINEAR copy of pre-swizzled image (1152 granules)
      const unsigned short* w1src = W1bf + (size_t)(hd * 4 + ph) * 9216;
#pragma unroll
      for (int it = 0; it < 4; ++it)
        g2l16(w1src + (size_t)((it * 4 + w) * 64 + lane) * 8, &Ws[(it * 4 + w) * 512]);
      if (w < 2)
        g2l16(w1src + (size_t)((16 + w) * 64 + lane) * 8, &Ws[(16 + w) * 512]);
      __syncthreads();  // W1q ready (and Ys on ph==0)

      // GEMM2: F^T = W1q @ Y^T. M=96(f), N=128(s), K=96.
      f32x4 acc2[6][2];
#pragma unroll
      for (int ft = 0; ft < 6; ++ft)
#pragma unroll
        for (int sp = 0; sp < 2; ++sp) acc2[ft][sp] = (f32x4){0.f, 0.f, 0.f, 0.f};
#pragma unroll
      for (int kb = 0; kb < 3; ++kb) {
        bf16x8 bfrg[2];
#pragma unroll
        for (int sp = 0; sp < 2; ++sp)
          bfrg[sp] = *(const bf16x8*)&Ys[kb * 4096 + ((w * 2 + sp) * 16 + r) * 32 + psw * 8];
#pragma unroll
        for (int ft = 0; ft < 6; ++ft) {
          bf16x8 afrg = *(const bf16x8*)&Ws[kb * 3072 + (ft * 16 + r) * 32 + psw * 8];
#pragma unroll
          for (int sp = 0; sp < 2; ++sp)
            acc2[ft][sp] = __builtin_amdgcn_mfma_f32_16x16x32_bf16(
                afrg, bfrg[sp], acc2[ft][sp], 0, 0, 0);
        }
      }
      // epilogue: +b1, relu, pack pairs, b64 write to Fs ([s][104], pad layout)
#pragma unroll
      for (int ft = 0; ft < 6; ++ft) {
        float4 bv = *(const float4*)&b1s[ph * 96 + ft * 16 + q * 4];
#pragma unroll
        for (int sp = 0; sp < 2; ++sp) {
          const int s = (w * 2 + sp) * 16 + r;
          float v0 = fmaxf(acc2[ft][sp][0] + bv.x, 0.f);
          float v1 = fmaxf(acc2[ft][sp][1] + bv.y, 0.f);
          float v2 = fmaxf(acc2[ft][sp][2] + bv.z, 0.f);
          float v3 = fmaxf(acc2[ft][sp][3] + bv.w, 0.f);
          uint2 pk;
          pk.x = pack_bf16_trunc(v0, v1);
          pk.y = pack_bf16_trunc(v2, v3);
          *(uint2*)((uint32_t*)&Fs[0] + s * 52 + ft * 8 + q * 2) = pk;
        }
      }
      __syncthreads();  // Fs ready; Ws (W1q) consumed

      // stage W2 quarter: LINEAR copy of pre-swizzled image
      const unsigned short* w2src = W2bf + (size_t)(hd * 4 + ph) * 9216;
#pragma unroll
      for (int it = 0; it < 4; ++it)
        g2l16(w2src + (size_t)((it * 4 + w) * 64 + lane) * 8, &Ws[(it * 4 + w) * 512]);
      if (w < 2)
        g2l16(w2src + (size_t)((16 + w) * 64 + lane) * 8, &Ws[(16 + w) * 512]);
      __syncthreads();  // Ws(W2q) ready

      // GEMM3 partial: M=128(s), N=96(h), K=96 this phase.
#pragma unroll
      for (int kb = 0; kb < 3; ++kb) {
        bf16x8 afrg[2];
#pragma unroll
        for (int sp = 0; sp < 2; ++sp)
          afrg[sp] = *(const bf16x8*)&Fs[((w * 2 + sp) * 16 + r) * 104 + kb * 32 + q * 8];
#pragma unroll
        for (int nt = 0; nt < 6; ++nt) {
          bf16x8 bfrg = *(const bf16x8*)&Ws[kb * 3072 + (nt * 16 + r) * 32 + psw * 8];
#pragma unroll
          for (int sp = 0; sp < 2; ++sp)
            acc3[sp][nt] = __builtin_amdgcn_mfma_f32_16x16x32_bf16(
                afrg[sp], bfrg, acc3[sp][nt], 0, 0, 0);
        }
      }
    }

    // ---- chunk pooling: online softmax accumulate ----
    // C-layout: h = nt*16 + r, s_local = (w*2+sp)*16 + q*4 + rg
#pragma unroll
    for (int nt = 0; nt < 6; ++nt) {
      const float b2v = b2s[nt * 16 + r];
      float lm = -3e30f;
#pragma unroll
      for (int sp = 0; sp < 2; ++sp) {
#pragma unroll
        for (int rg = 0; rg < 4; ++rg) {
          const int sl = (w * 2 + sp) * 16 + q * 4 + rg;
          float lg = acc3[sp][nt][rg] + b2v + bias_s[c * 128 + sl];
          lm = fmaxf(lm, lg);
        }
      }
      lm = fmaxf(lm, __shfl_xor(lm, 16));
      lm = fmaxf(lm, __shfl_xor(lm, 32));
      if (q == 0) redA[w][nt * 16 + r] = lm;
    }
    __syncthreads();  // chunk-max ready across waves
#pragma unroll
    for (int nt = 0; nt < 6; ++nt) {
      const int h = nt * 16 + r;
      // plane-layout swizzled Ys scalar read setup
      const int kbh = nt >> 1;                  // h>>5
      const int gh = (nt * 2 + (r >> 3)) & 3;   // (h>>3)&3
      const int hlo = r & 7;
      const float cm = fmaxf(fmaxf(redA[0][h], redA[1][h]),
                             fmaxf(redA[2][h], redA[3][h]));
      const float mnew = fmaxf(m_run[nt], cm);
      const float sc = __expf(m_run[nt] - mnew);
      m_run[nt] = mnew;
      float lacc = l_run[nt] * sc;
      float vacc = v_run[nt] * sc;
      const float b2v = b2s[h];
#pragma unroll
      for (int sp = 0; sp < 2; ++sp) {
#pragma unroll
        for (int rg = 0; rg < 4; ++rg) {
          const int sl = (w * 2 + sp) * 16 + q * 4 + rg;
          float lg = acc3[sp][nt][rg] + b2v + bias_s[c * 128 + sl];
          float e = __expf(lg - mnew);
          lacc += e;
          const int pos = gh ^ ((sl >> 1) & 3);
          vacc += e * bf16_to_f32(Ys[kbh * 4096 + sl * 32 + pos * 8 + hlo]);
        }
      }
      l_run[nt] = lacc;
      v_run[nt] = vacc;
    }
  }

  // ---- final reduce: sum l,v across q-groups then waves; out = v/l ----
  __syncthreads();  // redA/redB free
#pragma unroll
  for (int nt = 0; nt < 6; ++nt) {
    float ls = l_run[nt], vs = v_run[nt];
    ls += __shfl_xor(ls, 16);
    vs += __shfl_xor(vs, 16);
    ls += __shfl_xor(ls, 32);
    vs += __shfl_xor(vs, 32);
    if (q == 0) {
      redA[w][nt * 16 + r] = ls;
      redB[w][nt * 16 + r] = vs;
    }
  }
  __syncthreads();
  if (tid < 96) {
    float ls = redA[0][tid] + redA[1][tid] + redA[2][tid] + redA[3][tid];
    float vs = redB[0][tid] + redB[1][tid] + redB[2][tid] + redB[3][tid];
    out[(size_t)b * 768 + hd * 96 + tid] = vs / ls;
  }
}

// ---------------- launcher ----------------

extern "C" void kernel_launch(void* const* d_in, const int* in_sizes, int n_in,
                              void* d_out, int out_size, void* d_ws, size_t ws_size,
                              hipStream_t stream) {
  const float* X    = (const float*)d_in[0];
  const float* mask = (const float*)d_in[1];
  const float* P    = (const float*)d_in[2];
  const float* bP   = (const float*)d_in[3];
  const float* W1   = (const float*)d_in[4];
  const float* b1   = (const float*)d_in[5];
  const float* W2   = (const float*)d_in[6];
  const float* b2   = (const float*)d_in[7];
  float* out = (float*)d_out;
  (void)in_sizes; (void)n_in; (void)out_size; (void)ws_size;

  unsigned short* Xbf  = (unsigned short*)d_ws;
  unsigned short* Pbf  = Xbf + N_X;
  unsigned short* W1bf = Pbf + N_P;
  unsigned short* W2bf = W1bf + N_W1;
  unsigned short* Hi   = W2bf + N_W2;

  cast_f32_bf16<<<N_X / 4 / 256, 256, 0, stream>>>(X, Xbf, N_X / 4);
  cast_f32_bf16<<<N_P / 4 / 256, 256, 0, stream>>>(P, Pbf, N_P / 4);
  repack_w1<<<32, 256, 0, stream>>>(W1, W1bf);
  repack_w2<<<32, 256, 0, stream>>>(W2, W2bf);

  gemm_hi<<<3072, 256, 0, stream>>>(Xbf, Pbf, bP, Hi);
  mlp_pool<<<8 * 128, 256, 0, stream>>>(Hi, W1bf, W2bf, b1, b2, mask, out);
}